// Round 19
// baseline (188.604 us; speedup 1.0000x reference)
//
#include <hip/hip_runtime.h>

#define B_ 4
#define S_ 2048
#define D_ 1024
#define H_ 16
#define HD_ 64
#define M_ (B_*S_)      // 8192 rows
#define NQKV_ (3*D_)    // 3072

typedef _Float16 f16;
typedef __attribute__((ext_vector_type(4))) _Float16 f16x4;
typedef __attribute__((ext_vector_type(8))) _Float16 f16x8;
typedef __attribute__((ext_vector_type(4))) float f32x4;
typedef __attribute__((ext_vector_type(16))) float f32x16;
typedef __attribute__((ext_vector_type(2))) int i32x2;
typedef __attribute__((ext_vector_type(4))) int i32x4;

__device__ __forceinline__ void gload_lds16(const void* g, void* lds) {
  __builtin_amdgcn_global_load_lds(
      (const __attribute__((address_space(1))) void*)g,
      (__attribute__((address_space(3))) void*)lds, 16, 0, 0);
}

// ------- fused cast fp32 -> fp16 for x, W_qkv, W_o (outputs contiguous)
__global__ void cast3_kernel(const float* __restrict__ x,
                             const float* __restrict__ wqkv,
                             const float* __restrict__ wo,
                             f16* __restrict__ out) {
  size_t gi = (size_t)blockIdx.x * 2048 + (size_t)threadIdx.x * 8;
  const float* src;
  size_t off;
  if (gi < (size_t)M_ * D_)                       { src = x;    off = gi; }
  else if (gi < (size_t)M_ * D_ + (size_t)NQKV_ * D_) { src = wqkv; off = gi - (size_t)M_ * D_; }
  else                                            { src = wo;   off = gi - (size_t)M_ * D_ - (size_t)NQKV_ * D_; }
  float4 a = *reinterpret_cast<const float4*>(src + off);
  float4 b = *reinterpret_cast<const float4*>(src + off + 4);
  f16x8 o;
  o[0] = (f16)a.x; o[1] = (f16)a.y; o[2] = (f16)a.z; o[3] = (f16)a.w;
  o[4] = (f16)b.x; o[5] = (f16)b.y; o[6] = (f16)b.z; o[7] = (f16)b.w;
  *reinterpret_cast<f16x8*>(out + gi) = o;
}

// ---------------- RoPE trig table: tab[s][t] = {cos,sin}(pos[s]*invf(t))
__global__ void trig_kernel(const int* __restrict__ pos, float2* __restrict__ tab) {
  int idx = blockIdx.x * 256 + threadIdx.x;   // S_*32 threads
  int s = idx >> 5, t = idx & 31;
  float p = (float)pos[s];
  float invf = exp2f((float)t * -0.4152410118609203f);  // -log2(10000)/32
  float sn, cs;
  sincosf(p * invf, &sn, &cs);
  tab[idx] = float2{cs, sn};
}

// ---------------- GEMM C[m,n] = sum_k A[m,k]*Bt[n,k] ----------------
// (unchanged — swizzle-fixed counted-vmcnt ring-2, BK=32, 4 blocks/CU)
template <int MODE>
__global__ __launch_bounds__(256, 4)
void gemm_bt(const f16* __restrict__ A, const f16* __restrict__ Bt,
             void* __restrict__ Cout, const float2* __restrict__ tab,
             f16* __restrict__ kout, f16* __restrict__ vtout,
             int M, int N, int K) {
  constexpr int MI = (MODE == 0) ? 4 : 2;   // 16-row A-frags per wave
  constexpr int BP = (MODE == 0) ? 2 : 1;   // B staging passes; BN = 64*BP
  __shared__ __align__(16) f16 As[2][128 * 32];
  __shared__ __align__(16) f16 Bs[2][BP * 64 * 32];
  const int tid = threadIdx.x;
  const int w = tid >> 6, l = tid & 63;
  const int nM = M >> 7;
  const int bm = (int)(blockIdx.x % nM) << 7;
  const int bn = (int)(blockIdx.x / nM) * (BP * 64);
  const int wrow = (MODE == 0) ? ((w >> 1) << 6) : (w << 5);
  const int wcol = (MODE == 0) ? ((w & 1) << 6) : 0;
  const int lr = l & 15;
  const int lk = (l >> 4) << 3;     // 0,8,16,24
  const int orow = (l >> 4) << 2;
  const int swzr = ((lr >> 1) & 3) << 3;   // read-side XOR, key=(row>>1)&3
  const int NT = K >> 5;            // 32

  f32x4 acc[MI][4];
  #pragma unroll
  for (int i = 0; i < MI; ++i)
    #pragma unroll
    for (int j = 0; j < 4; ++j) acc[i][j] = f32x4{0.f, 0.f, 0.f, 0.f};

  const int srow4 = tid >> 2;            // 4 threads/row, 16B each
  const int ssw = ((tid & 3) * 8) ^ (((srow4 >> 1) & 3) << 3);

#define STAGE(t_) do {                                                    \
    const int buf_ = (t_) & 1; const int k0_ = (t_) << 5;                 \
    _Pragma("unroll")                                                     \
    for (int p = 0; p < 2; ++p)                                           \
      gload_lds16(A + (size_t)(bm + p * 64 + srow4) * K + k0_ + ssw,      \
                  (void*)(&As[buf_][(p * 256 + tid) * 8]));               \
    _Pragma("unroll")                                                     \
    for (int p = 0; p < BP; ++p)                                          \
      gload_lds16(Bt + (size_t)(bn + p * 64 + srow4) * K + k0_ + ssw,     \
                  (void*)(&Bs[buf_][(p * 256 + tid) * 8]));               \
  } while (0)

  STAGE(0);

  for (int t = 0; t < NT; ++t) {
    if (t + 1 < NT) {
      STAGE(t + 1);
      if constexpr (MODE == 0)
        asm volatile("s_waitcnt vmcnt(4)" ::: "memory");   // tile t landed
      else
        asm volatile("s_waitcnt vmcnt(3)" ::: "memory");
    } else {
      asm volatile("s_waitcnt vmcnt(0)" ::: "memory");
    }
    __builtin_amdgcn_sched_barrier(0);
    __builtin_amdgcn_s_barrier();       // tile t visible to all waves
    __builtin_amdgcn_sched_barrier(0);

    const f16* Asc = As[t & 1];
    const f16* Bsc = Bs[t & 1];
    f16x8 af[MI], bf[4];
    #pragma unroll
    for (int mi = 0; mi < MI; ++mi)
      af[mi] = *reinterpret_cast<const f16x8*>(
          Asc + (wrow + mi * 16 + lr) * 32 + (lk ^ swzr));
    #pragma unroll
    for (int ni = 0; ni < 4; ++ni)
      bf[ni] = *reinterpret_cast<const f16x8*>(
          Bsc + (wcol + ni * 16 + lr) * 32 + (lk ^ swzr));
    #pragma unroll
    for (int mi = 0; mi < MI; ++mi)
      #pragma unroll
      for (int ni = 0; ni < 4; ++ni)
        acc[mi][ni] = __builtin_amdgcn_mfma_f32_16x16x32_f16(bf[ni], af[mi], acc[mi][ni], 0, 0, 0);

    __builtin_amdgcn_sched_barrier(0);
    __builtin_amdgcn_s_barrier();       // all reads of buf[t&1] done
    __builtin_amdgcn_sched_barrier(0);
  }
#undef STAGE

  if (MODE == 0) {
    const int which = bn >> 10;                    // uniform per block
    const int h = ((bn + wcol) >> 6) & (H_ - 1);   // uniform per wave
    if (which < 2) {                               // Q or K: fused RoPE
      f16* dst = which ? kout : (f16*)Cout;
      const float qs = which ? 1.0f : 0.125f * 1.4426950408889634f;  // (1/8)*log2e
      #pragma unroll
      for (int mi = 0; mi < MI; ++mi) {
        int m = bm + wrow + mi * 16 + lr;
        int b = m >> 11, s = m & (S_ - 1);
        size_t rowbase = ((size_t)(b * H_ + h) * S_ + s) * HD_;
        const float4* trow = reinterpret_cast<const float4*>(tab + (size_t)s * 32);
        #pragma unroll
        for (int ni = 0; ni < 4; ++ni) {
          int d0 = ni * 16 + orow;                 // multiple of 4
          float4 cssn = trow[d0 >> 2];
          float x0 = acc[mi][ni][0], x1 = acc[mi][ni][1];
          float x2 = acc[mi][ni][2], x3 = acc[mi][ni][3];
          f16x4 ov;
          ov[0] = (f16)((x0 * cssn.x - x1 * cssn.y) * qs);
          ov[1] = (f16)((x1 * cssn.x + x0 * cssn.y) * qs);
          ov[2] = (f16)((x2 * cssn.z - x3 * cssn.w) * qs);
          ov[3] = (f16)((x3 * cssn.z + x2 * cssn.w) * qs);
          *reinterpret_cast<f16x4*>(&dst[rowbase + d0]) = ov;
        }
      }
    } else {                                       // V: direct transposed write
      #pragma unroll
      for (int mi = 0; mi < MI; ++mi) {
        int m = bm + wrow + mi * 16 + lr;
        int b = m >> 11, s = m & (S_ - 1);
        size_t base = (size_t)(b * H_ + h) * (HD_ * S_) + s;
        #pragma unroll
        for (int ni = 0; ni < 4; ++ni)
          #pragma unroll
          for (int r = 0; r < 4; ++r)
            vtout[base + (size_t)(ni * 16 + orow + r) * S_] = (f16)acc[mi][ni][r];
      }
    }
  } else {
    float* C = (float*)Cout;
    #pragma unroll
    for (int mi = 0; mi < MI; ++mi) {
      int m = bm + wrow + mi * 16 + lr;
      #pragma unroll
      for (int ni = 0; ni < 4; ++ni) {
        int n = bn + wcol + ni * 16 + orow;
        *reinterpret_cast<float4*>(&C[(size_t)m * N + n]) =
            float4{acc[mi][ni][0], acc[mi][ni][1], acc[mi][ni][2], acc[mi][ni][3]};
      }
    }
  }
}

// ---------------- flash attention (causal), 32x32, SPLIT-KV ---------
// R15 body, but each q-tile's KV range is split into 2 equal chunks
// (qt+1 tiles each, <=16): grid 2048 = 4 resident + 4 queued blocks
// per CU -> refill eliminates the async-finish tail that capped
// occupancy at 31% (R16/R17 diagnosis; R17's fix halved residency,
// this one keeps it). Each chunk writes locally-normalized partial
// o (f16) + (m,l) f32; merge_kernel combines. Chunk0 = tiles
// [0,qt+1) (diagonal only when qt=0, generic mask covers it);
// chunk1 = tiles [qt+1,2qt+2) (has the diagonal; wave-skip active).
__global__ __launch_bounds__(256, 4)
void attn_kernel(const f16* __restrict__ q, const f16* __restrict__ k,
                 const f16* __restrict__ vt,
                 f16* __restrict__ oA, f16* __restrict__ oB,
                 float2* __restrict__ mlA, float2* __restrict__ mlB) {
  __shared__ __align__(16) f16 Ks[64 * 64];
  __shared__ __align__(16) f16 Vs[64 * 64];     // [d][kv]
  const int tid = threadIdx.x, wq = tid >> 6, l = tid & 63;
  const int lq = l & 31, hi = l >> 5;
  const int bh = blockIdx.x & 63;
  const int rest = (int)(blockIdx.x >> 6);      // 0..31
  const int chunk = rest & 1;
  const int qt = 15 - (rest >> 1);              // heavy q-tiles first
  const int q0 = qt << 7;
  const int it0 = chunk ? (qt + 1) : 0;
  const int it1 = chunk ? (2 * qt + 2) : (qt + 1);
  const size_t bhoff = (size_t)bh * (S_ * HD_);
  const size_t vtoff = (size_t)bh * (HD_ * S_);
  const int srow = tid >> 3;
  const int sc8 = (tid & 7) * 8;
  const int ssw = sc8 ^ ((srow & 7) << 3);      // swizzled source col
  const int swz = (lq & 7) << 3;                // read-side XOR
  const int h = bh & (H_ - 1), b = bh >> 4;
  const int wqmin = q0 + wq * 32;
  const int qrow = wqmin + lq;                  // this lane's q-row

  f16x8 qf[4];
  #pragma unroll
  for (int s = 0; s < 4; ++s)
    qf[s] = *reinterpret_cast<const f16x8*>(q + bhoff + (size_t)qrow * HD_ + s * 16 + hi * 8);

  f32x16 o[2];
  float m_run = -1e30f, l_run = 0.f;
  #pragma unroll
  for (int i = 0; i < 2; ++i)
    #pragma unroll
    for (int r = 0; r < 16; ++r) o[i][r] = 0.f;

  for (int it = it0; it < it1; ++it) {
    const int kv0 = it << 6;
    __syncthreads();
    #pragma unroll
    for (int i = 0; i < 2; ++i) {
      gload_lds16(k + bhoff + (size_t)(kv0 + i * 32 + srow) * HD_ + ssw,
                  (void*)(Ks + (i * 256 + wq * 64) * 8));
      gload_lds16(vt + vtoff + (size_t)(i * 32 + srow) * S_ + kv0 + ssw,
                  (void*)(Vs + (i * 256 + wq * 64) * 8));
    }
    __syncthreads();

    if (kv0 <= wqmin + 31) {   // wave-uniform causal skip
      // S^T: D[col=q=lq][row = kh*32 + (r&3) + 8*(r>>2) + 4*hi]
      f32x16 sacc[2];
      #pragma unroll
      for (int kh = 0; kh < 2; ++kh) {
        #pragma unroll
        for (int r = 0; r < 16; ++r) sacc[kh][r] = 0.f;
        #pragma unroll
        for (int s = 0; s < 4; ++s) {
          f16x8 kf = *reinterpret_cast<const f16x8*>(
              Ks + (kh * 32 + lq) * 64 + ((s * 16 + hi * 8) ^ swz));
          sacc[kh] = __builtin_amdgcn_mfma_f32_32x32x16_f16(kf, qf[s], sacc[kh], 0, 0, 0);
        }
      }
      if (kv0 + 63 >= wqmin) {   // diagonal straddle: element mask
        #pragma unroll
        for (int kh = 0; kh < 2; ++kh)
          #pragma unroll
          for (int r = 0; r < 16; ++r) {
            int kvg = kv0 + kh * 32 + (r & 3) + 8 * (r >> 2) + 4 * hi;
            if (kvg > qrow) sacc[kh][r] = -1e30f;
          }
      }

      // online softmax with defer-max (T13, THR=8 in log2 units)
      float mloc = -1e30f;
      #pragma unroll
      for (int kh = 0; kh < 2; ++kh)
        #pragma unroll
        for (int r = 0; r < 16; ++r) mloc = fmaxf(mloc, sacc[kh][r]);
      mloc = fmaxf(mloc, __shfl_xor(mloc, 32));
      if (__any(mloc > m_run + 8.f)) {
        float mn = fmaxf(m_run, mloc);
        float scale = exp2f(m_run - mn);
        m_run = mn;
        l_run *= scale;
        #pragma unroll
        for (int i = 0; i < 2; ++i)
          #pragma unroll
          for (int r = 0; r < 16; ++r) o[i][r] *= scale;
      }
      float sloc = 0.f;
      #pragma unroll
      for (int kh = 0; kh < 2; ++kh)
        #pragma unroll
        for (int r = 0; r < 16; ++r) {
          sacc[kh][r] = exp2f(sacc[kh][r] - m_run);
          sloc += sacc[kh][r];
        }
      sloc += __shfl_xor(sloc, 32);
      l_run += sloc;

      // P -> PV B-fragments fully in-register:
      // pf[ks][j] = P[lq][16*ks + 8*hi + j]
      f16x8 pf[4];
      #pragma unroll
      for (int ks = 0; ks < 4; ++ks) {
        const int khh = ks >> 1;
        f16x4 pA, pB;
        #pragma unroll
        for (int r = 0; r < 4; ++r) {
          pA[r] = (f16)sacc[khh][(ks & 1) * 8 + r];
          pB[r] = (f16)sacc[khh][(ks & 1) * 8 + 4 + r];
        }
        i32x2 ia = __builtin_bit_cast(i32x2, pA);
        i32x2 ib = __builtin_bit_cast(i32x2, pB);
        i32x2 oth, rcv, lo2, hh2;
        oth.x = hi ? ia.x : ib.x;
        oth.y = hi ? ia.y : ib.y;
        rcv.x = __shfl_xor(oth.x, 32);
        rcv.y = __shfl_xor(oth.y, 32);
        lo2.x = hi ? rcv.x : ia.x;
        lo2.y = hi ? rcv.y : ia.y;
        hh2.x = hi ? ib.x : rcv.x;
        hh2.y = hi ? ib.y : rcv.y;
        i32x4 full{lo2.x, lo2.y, hh2.x, hh2.y};
        pf[ks] = __builtin_bit_cast(f16x8, full);
      }

      // O^T += V^T @ P^T
      #pragma unroll
      for (int dh = 0; dh < 2; ++dh)
        #pragma unroll
        for (int s2 = 0; s2 < 4; ++s2) {
          f16x8 vf = *reinterpret_cast<const f16x8*>(
              Vs + (dh * 32 + lq) * 64 + ((s2 * 16 + hi * 8) ^ swz));
          o[dh] = __builtin_amdgcn_mfma_f32_32x32x16_f16(vf, pf[s2], o[dh], 0, 0, 0);
        }
    }
  }

  // epilogue: locally-normalized partial + (m,l) per row
  f16* dst = chunk ? oB : oA;
  float rl = (l_run > 0.f) ? (1.0f / l_run) : 0.f;
  #pragma unroll
  for (int dh = 0; dh < 2; ++dh)
    #pragma unroll
    for (int qd = 0; qd < 4; ++qd) {
      f16x4 ov;
      #pragma unroll
      for (int r = 0; r < 4; ++r) ov[r] = (f16)(o[dh][qd * 4 + r] * rl);
      int d0 = dh * 32 + qd * 8 + hi * 4;
      *reinterpret_cast<f16x4*>(
          &dst[(size_t)(b * S_ + qrow) * D_ + h * HD_ + d0]) = ov;
    }
  if (hi == 0) {
    float2* ml = chunk ? mlB : mlA;
    ml[((b * H_ + h) << 11) + qrow] = float2{m_run, l_run};
  }
}

// ---------------- split-KV merge: out = (sA*oA + sB*oB)/(sA+sB) ----
__global__ void merge_kernel(const f16* __restrict__ oA, const f16* __restrict__ oB,
                             const float2* __restrict__ mlA, const float2* __restrict__ mlB,
                             f16* __restrict__ out) {
  size_t addr = ((size_t)blockIdx.x * 256 + threadIdx.x) * 8;  // elem in (B,S,D)
  int hh = (int)((addr >> 6) & 15);
  int ss = (int)((addr >> 10) & 2047);
  int bb = (int)(addr >> 21);
  int mlidx = ((bb * H_ + hh) << 11) + ss;
  float2 a = mlA[mlidx], c = mlB[mlidx];
  float m = fmaxf(a.x, c.x);
  float sA = exp2f(a.x - m) * a.y;
  float sB = exp2f(c.x - m) * c.y;
  float inv = 1.0f / (sA + sB);
  float wA = sA * inv, wB = sB * inv;
  f16x8 va = *reinterpret_cast<const f16x8*>(oA + addr);
  f16x8 vb = *reinterpret_cast<const f16x8*>(oB + addr);
  f16x8 o;
  #pragma unroll
  for (int j = 0; j < 8; ++j)
    o[j] = (f16)(wA * (float)va[j] + wB * (float)vb[j]);
  *reinterpret_cast<f16x8*>(out + addr) = o;
}

// ---------------- launch --------------------------------------------
extern "C" void kernel_launch(void* const* d_in, const int* in_sizes, int n_in,
                              void* d_out, int out_size, void* d_ws, size_t ws_size,
                              hipStream_t stream) {
  const float* x    = (const float*)d_in[0];
  const int*   pos  = (const int*)d_in[1];
  const float* wqkv = (const float*)d_in[2];
  const float* wo   = (const float*)d_in[3];
  float* out = (float*)d_out;

  const size_t BHSD = (size_t)B_ * H_ * S_ * HD_;   // 8388608
  f16* xb    = (f16*)d_ws;                 // M_*D_ (dead after gemm0 -> oB)
  f16* wqkvb = xb + (size_t)M_ * D_;       // NQKV_*D_ (dead after gemm0 -> ml)
  f16* wob   = wqkvb + (size_t)NQKV_ * D_; // D_*D_
  f16* qb    = wob + (size_t)D_ * D_;      // BHSD
  f16* kb    = qb + BHSD;                  // BHSD
  f16* vtb   = kb + BHSD;                  // BHSD (B,H,hd,S)
  f16* attnb = vtb + BHSD;                 // BHSD (oA partial, then merged)
  float2* tab = (float2*)(attnb + BHSD);   // S_*32 float2 = 512 KB
  // split-KV scratch (reuses dead buffers):
  f16* oB = xb;                            // BHSD f16 = 16.7MB (== xb size)
  float2* mlA = (float2*)wqkvb;            // 131072 float2 = 1MB
  float2* mlB = mlA + (size_t)B_ * H_ * S_;

  cast3_kernel<<<6144, 256, 0, stream>>>(x, wqkv, wo, xb);
  trig_kernel<<<(S_ * 32) / 256, 256, 0, stream>>>(pos, tab);

  gemm_bt<0><<<(M_ / 128) * (NQKV_ / 128), 256, 0, stream>>>(
      xb, wqkvb, (void*)qb, tab, kb, vtb, M_, NQKV_, D_);

  attn_kernel<<<64 * 32, 256, 0, stream>>>(qb, kb, vtb, attnb, oB, mlA, mlB);
  merge_kernel<<<(int)(BHSD / 8 / 256), 256, 0, stream>>>(attnb, oB, mlA, mlB, attnb);

  gemm_bt<1><<<(M_ / 128) * (D_ / 64), 256, 0, stream>>>(
      attnb, wob, (void*)out, nullptr, nullptr, nullptr, M_, D_, D_);
}

// Round 20
// 183.234 us; speedup vs baseline: 1.0293x; 1.0293x over previous
//
#include <hip/hip_runtime.h>

#define B_ 4
#define S_ 2048
#define D_ 1024
#define H_ 16
#define HD_ 64
#define M_ (B_*S_)      // 8192 rows
#define NQKV_ (3*D_)    // 3072

typedef _Float16 f16;
typedef __attribute__((ext_vector_type(4))) _Float16 f16x4;
typedef __attribute__((ext_vector_type(8))) _Float16 f16x8;
typedef __attribute__((ext_vector_type(4))) float f32x4;
typedef __attribute__((ext_vector_type(16))) float f32x16;
typedef __attribute__((ext_vector_type(2))) int i32x2;
typedef __attribute__((ext_vector_type(4))) int i32x4;

__device__ __forceinline__ void gload_lds16(const void* g, void* lds) {
  __builtin_amdgcn_global_load_lds(
      (const __attribute__((address_space(1))) void*)g,
      (__attribute__((address_space(3))) void*)lds, 16, 0, 0);
}

// ------- fused cast fp32 -> fp16 for x, W_qkv, W_o (outputs contiguous)
__global__ void cast3_kernel(const float* __restrict__ x,
                             const float* __restrict__ wqkv,
                             const float* __restrict__ wo,
                             f16* __restrict__ out) {
  size_t gi = (size_t)blockIdx.x * 2048 + (size_t)threadIdx.x * 8;
  const float* src;
  size_t off;
  if (gi < (size_t)M_ * D_)                       { src = x;    off = gi; }
  else if (gi < (size_t)M_ * D_ + (size_t)NQKV_ * D_) { src = wqkv; off = gi - (size_t)M_ * D_; }
  else                                            { src = wo;   off = gi - (size_t)M_ * D_ - (size_t)NQKV_ * D_; }
  float4 a = *reinterpret_cast<const float4*>(src + off);
  float4 b = *reinterpret_cast<const float4*>(src + off + 4);
  f16x8 o;
  o[0] = (f16)a.x; o[1] = (f16)a.y; o[2] = (f16)a.z; o[3] = (f16)a.w;
  o[4] = (f16)b.x; o[5] = (f16)b.y; o[6] = (f16)b.z; o[7] = (f16)b.w;
  *reinterpret_cast<f16x8*>(out + gi) = o;
}

// ---------------- RoPE trig table: tab[s][t] = {cos,sin}(pos[s]*invf(t))
__global__ void trig_kernel(const int* __restrict__ pos, float2* __restrict__ tab) {
  int idx = blockIdx.x * 256 + threadIdx.x;   // S_*32 threads
  int s = idx >> 5, t = idx & 31;
  float p = (float)pos[s];
  float invf = exp2f((float)t * -0.4152410118609203f);  // -log2(10000)/32
  float sn, cs;
  sincosf(p * invf, &sn, &cs);
  tab[idx] = float2{cs, sn};
}

// ---------------- GEMM C[m,n] = sum_k A[m,k]*Bt[n,k] ----------------
// (unchanged — swizzle-fixed counted-vmcnt ring-2, BK=32, 4 blocks/CU)
template <int MODE>
__global__ __launch_bounds__(256, 4)
void gemm_bt(const f16* __restrict__ A, const f16* __restrict__ Bt,
             void* __restrict__ Cout, const float2* __restrict__ tab,
             f16* __restrict__ kout, f16* __restrict__ vtout,
             int M, int N, int K) {
  constexpr int MI = (MODE == 0) ? 4 : 2;   // 16-row A-frags per wave
  constexpr int BP = (MODE == 0) ? 2 : 1;   // B staging passes; BN = 64*BP
  __shared__ __align__(16) f16 As[2][128 * 32];
  __shared__ __align__(16) f16 Bs[2][BP * 64 * 32];
  const int tid = threadIdx.x;
  const int w = tid >> 6, l = tid & 63;
  const int nM = M >> 7;
  const int bm = (int)(blockIdx.x % nM) << 7;
  const int bn = (int)(blockIdx.x / nM) * (BP * 64);
  const int wrow = (MODE == 0) ? ((w >> 1) << 6) : (w << 5);
  const int wcol = (MODE == 0) ? ((w & 1) << 6) : 0;
  const int lr = l & 15;
  const int lk = (l >> 4) << 3;     // 0,8,16,24
  const int orow = (l >> 4) << 2;
  const int swzr = ((lr >> 1) & 3) << 3;   // read-side XOR, key=(row>>1)&3
  const int NT = K >> 5;            // 32

  f32x4 acc[MI][4];
  #pragma unroll
  for (int i = 0; i < MI; ++i)
    #pragma unroll
    for (int j = 0; j < 4; ++j) acc[i][j] = f32x4{0.f, 0.f, 0.f, 0.f};

  const int srow4 = tid >> 2;            // 4 threads/row, 16B each
  const int ssw = ((tid & 3) * 8) ^ (((srow4 >> 1) & 3) << 3);

#define STAGE(t_) do {                                                    \
    const int buf_ = (t_) & 1; const int k0_ = (t_) << 5;                 \
    _Pragma("unroll")                                                     \
    for (int p = 0; p < 2; ++p)                                           \
      gload_lds16(A + (size_t)(bm + p * 64 + srow4) * K + k0_ + ssw,      \
                  (void*)(&As[buf_][(p * 256 + tid) * 8]));               \
    _Pragma("unroll")                                                     \
    for (int p = 0; p < BP; ++p)                                          \
      gload_lds16(Bt + (size_t)(bn + p * 64 + srow4) * K + k0_ + ssw,     \
                  (void*)(&Bs[buf_][(p * 256 + tid) * 8]));               \
  } while (0)

  STAGE(0);

  for (int t = 0; t < NT; ++t) {
    if (t + 1 < NT) {
      STAGE(t + 1);
      if constexpr (MODE == 0)
        asm volatile("s_waitcnt vmcnt(4)" ::: "memory");   // tile t landed
      else
        asm volatile("s_waitcnt vmcnt(3)" ::: "memory");
    } else {
      asm volatile("s_waitcnt vmcnt(0)" ::: "memory");
    }
    __builtin_amdgcn_sched_barrier(0);
    __builtin_amdgcn_s_barrier();       // tile t visible to all waves
    __builtin_amdgcn_sched_barrier(0);

    const f16* Asc = As[t & 1];
    const f16* Bsc = Bs[t & 1];
    f16x8 af[MI], bf[4];
    #pragma unroll
    for (int mi = 0; mi < MI; ++mi)
      af[mi] = *reinterpret_cast<const f16x8*>(
          Asc + (wrow + mi * 16 + lr) * 32 + (lk ^ swzr));
    #pragma unroll
    for (int ni = 0; ni < 4; ++ni)
      bf[ni] = *reinterpret_cast<const f16x8*>(
          Bsc + (wcol + ni * 16 + lr) * 32 + (lk ^ swzr));
    #pragma unroll
    for (int mi = 0; mi < MI; ++mi)
      #pragma unroll
      for (int ni = 0; ni < 4; ++ni)
        acc[mi][ni] = __builtin_amdgcn_mfma_f32_16x16x32_f16(bf[ni], af[mi], acc[mi][ni], 0, 0, 0);

    __builtin_amdgcn_sched_barrier(0);
    __builtin_amdgcn_s_barrier();       // all reads of buf[t&1] done
    __builtin_amdgcn_sched_barrier(0);
  }
#undef STAGE

  if (MODE == 0) {
    const int which = bn >> 10;                    // uniform per block
    const int h = ((bn + wcol) >> 6) & (H_ - 1);   // uniform per wave
    if (which < 2) {                               // Q or K: fused RoPE
      f16* dst = which ? kout : (f16*)Cout;
      const float qs = which ? 1.0f : 0.125f * 1.4426950408889634f;  // (1/8)*log2e
      #pragma unroll
      for (int mi = 0; mi < MI; ++mi) {
        int m = bm + wrow + mi * 16 + lr;
        int b = m >> 11, s = m & (S_ - 1);
        size_t rowbase = ((size_t)(b * H_ + h) * S_ + s) * HD_;
        const float4* trow = reinterpret_cast<const float4*>(tab + (size_t)s * 32);
        #pragma unroll
        for (int ni = 0; ni < 4; ++ni) {
          int d0 = ni * 16 + orow;                 // multiple of 4
          float4 cssn = trow[d0 >> 2];
          float x0 = acc[mi][ni][0], x1 = acc[mi][ni][1];
          float x2 = acc[mi][ni][2], x3 = acc[mi][ni][3];
          f16x4 ov;
          ov[0] = (f16)((x0 * cssn.x - x1 * cssn.y) * qs);
          ov[1] = (f16)((x1 * cssn.x + x0 * cssn.y) * qs);
          ov[2] = (f16)((x2 * cssn.z - x3 * cssn.w) * qs);
          ov[3] = (f16)((x3 * cssn.z + x2 * cssn.w) * qs);
          *reinterpret_cast<f16x4*>(&dst[rowbase + d0]) = ov;
        }
      }
    } else {                                       // V: direct transposed write
      #pragma unroll
      for (int mi = 0; mi < MI; ++mi) {
        int m = bm + wrow + mi * 16 + lr;
        int b = m >> 11, s = m & (S_ - 1);
        size_t base = (size_t)(b * H_ + h) * (HD_ * S_) + s;
        #pragma unroll
        for (int ni = 0; ni < 4; ++ni)
          #pragma unroll
          for (int r = 0; r < 4; ++r)
            vtout[base + (size_t)(ni * 16 + orow + r) * S_] = (f16)acc[mi][ni][r];
      }
    }
  } else {
    float* C = (float*)Cout;
    #pragma unroll
    for (int mi = 0; mi < MI; ++mi) {
      int m = bm + wrow + mi * 16 + lr;
      #pragma unroll
      for (int ni = 0; ni < 4; ++ni) {
        int n = bn + wcol + ni * 16 + orow;
        *reinterpret_cast<float4*>(&C[(size_t)m * N + n]) =
            float4{acc[mi][ni][0], acc[mi][ni][1], acc[mi][ni][2], acc[mi][ni][3]};
      }
    }
  }
}

// ---------------- flash attention (causal), 32x32 MFMA form ---------
// R18 best-measured version (80.1 us) + T5 s_setprio(1) around the
// MFMA clusters. Mechanism: 4 co-resident BLOCKS per CU sit at
// different tile indices (one staging, others computing) — setprio
// lets the CU scheduler favor the MFMA-issuing wave over waves doing
// staging/VALU, the m191 attn regime (+4-7%). Zero correctness risk.
// All structural alternatives measured worse: ring-2 (82.4), pairing
// (94.3), split-KV+merge (188.6 total), LDS-free (154.9), MFMA
// row-sum (98.5, spilled).
__global__ __launch_bounds__(256, 4)
void attn_kernel(const f16* __restrict__ q, const f16* __restrict__ k,
                 const f16* __restrict__ vt, f16* __restrict__ attn_out) {
  __shared__ __align__(16) f16 Ks[64 * 64];
  __shared__ __align__(16) f16 Vs[64 * 64];     // [d][kv]
  const int tid = threadIdx.x, wq = tid >> 6, l = tid & 63;
  const int lq = l & 31, hi = l >> 5;
  const int bh = blockIdx.x & 63;
  const int qt = 15 - (int)(blockIdx.x >> 6);   // heavy tiles first
  const int q0 = qt << 7;
  const size_t bhoff = (size_t)bh * (S_ * HD_);
  const size_t vtoff = (size_t)bh * (HD_ * S_);
  const int srow = tid >> 3;
  const int sc8 = (tid & 7) * 8;
  const int ssw = sc8 ^ ((srow & 7) << 3);      // swizzled source col
  const int swz = (lq & 7) << 3;                // read-side XOR
  const int h = bh & (H_ - 1), b = bh >> 4;
  const int wqmin = q0 + wq * 32;
  const int qrow = wqmin + lq;                  // this lane's q-row

  f16x8 qf[4];
  #pragma unroll
  for (int s = 0; s < 4; ++s)
    qf[s] = *reinterpret_cast<const f16x8*>(q + bhoff + (size_t)qrow * HD_ + s * 16 + hi * 8);

  f32x16 o[2];
  float m_run = -1e30f, l_run = 0.f;
  #pragma unroll
  for (int i = 0; i < 2; ++i)
    #pragma unroll
    for (int r = 0; r < 16; ++r) o[i][r] = 0.f;

  const int ntiles = 2 * qt + 2;
  for (int it = 0; it < ntiles; ++it) {
    const int kv0 = it << 6;
    __syncthreads();
    #pragma unroll
    for (int i = 0; i < 2; ++i) {
      gload_lds16(k + bhoff + (size_t)(kv0 + i * 32 + srow) * HD_ + ssw,
                  (void*)(Ks + (i * 256 + wq * 64) * 8));
      gload_lds16(vt + vtoff + (size_t)(i * 32 + srow) * S_ + kv0 + ssw,
                  (void*)(Vs + (i * 256 + wq * 64) * 8));
    }
    __syncthreads();

    if (kv0 <= wqmin + 31) {   // wave-uniform causal skip
      // S^T: D[col=q=lq][row = kh*32 + (r&3) + 8*(r>>2) + 4*hi]
      f32x16 sacc[2];
      __builtin_amdgcn_s_setprio(1);            // T5: favor MFMA wave
      #pragma unroll
      for (int kh = 0; kh < 2; ++kh) {
        #pragma unroll
        for (int r = 0; r < 16; ++r) sacc[kh][r] = 0.f;
        #pragma unroll
        for (int s = 0; s < 4; ++s) {
          f16x8 kf = *reinterpret_cast<const f16x8*>(
              Ks + (kh * 32 + lq) * 64 + ((s * 16 + hi * 8) ^ swz));
          sacc[kh] = __builtin_amdgcn_mfma_f32_32x32x16_f16(kf, qf[s], sacc[kh], 0, 0, 0);
        }
      }
      __builtin_amdgcn_s_setprio(0);
      if (kv0 + 63 >= wqmin) {   // diagonal straddle: element mask
        #pragma unroll
        for (int kh = 0; kh < 2; ++kh)
          #pragma unroll
          for (int r = 0; r < 16; ++r) {
            int kvg = kv0 + kh * 32 + (r & 3) + 8 * (r >> 2) + 4 * hi;
            if (kvg > qrow) sacc[kh][r] = -1e30f;
          }
      }

      // online softmax with defer-max (T13, THR=8 in log2 units)
      float mloc = -1e30f;
      #pragma unroll
      for (int kh = 0; kh < 2; ++kh)
        #pragma unroll
        for (int r = 0; r < 16; ++r) mloc = fmaxf(mloc, sacc[kh][r]);
      mloc = fmaxf(mloc, __shfl_xor(mloc, 32));
      if (__any(mloc > m_run + 8.f)) {
        float mn = fmaxf(m_run, mloc);
        float scale = exp2f(m_run - mn);
        m_run = mn;
        l_run *= scale;
        #pragma unroll
        for (int i = 0; i < 2; ++i)
          #pragma unroll
          for (int r = 0; r < 16; ++r) o[i][r] *= scale;
      }
      float sloc = 0.f;
      #pragma unroll
      for (int kh = 0; kh < 2; ++kh)
        #pragma unroll
        for (int r = 0; r < 16; ++r) {
          sacc[kh][r] = exp2f(sacc[kh][r] - m_run);
          sloc += sacc[kh][r];
        }
      sloc += __shfl_xor(sloc, 32);
      l_run += sloc;

      // P -> PV B-fragments fully in-register:
      // pf[ks][j] = P[lq][16*ks + 8*hi + j]
      f16x8 pf[4];
      #pragma unroll
      for (int ks = 0; ks < 4; ++ks) {
        const int khh = ks >> 1;
        f16x4 pA, pB;
        #pragma unroll
        for (int r = 0; r < 4; ++r) {
          pA[r] = (f16)sacc[khh][(ks & 1) * 8 + r];
          pB[r] = (f16)sacc[khh][(ks & 1) * 8 + 4 + r];
        }
        i32x2 ia = __builtin_bit_cast(i32x2, pA);
        i32x2 ib = __builtin_bit_cast(i32x2, pB);
        i32x2 oth, rcv, lo2, hh2;
        oth.x = hi ? ia.x : ib.x;
        oth.y = hi ? ia.y : ib.y;
        rcv.x = __shfl_xor(oth.x, 32);
        rcv.y = __shfl_xor(oth.y, 32);
        lo2.x = hi ? rcv.x : ia.x;
        lo2.y = hi ? rcv.y : ia.y;
        hh2.x = hi ? ib.x : rcv.x;
        hh2.y = hi ? ib.y : rcv.y;
        i32x4 full{lo2.x, lo2.y, hh2.x, hh2.y};
        pf[ks] = __builtin_bit_cast(f16x8, full);
      }

      // O^T += V^T @ P^T
      __builtin_amdgcn_s_setprio(1);            // T5
      #pragma unroll
      for (int dh = 0; dh < 2; ++dh)
        #pragma unroll
        for (int s2 = 0; s2 < 4; ++s2) {
          f16x8 vf = *reinterpret_cast<const f16x8*>(
              Vs + (dh * 32 + lq) * 64 + ((s2 * 16 + hi * 8) ^ swz));
          o[dh] = __builtin_amdgcn_mfma_f32_32x32x16_f16(vf, pf[s2], o[dh], 0, 0, 0);
        }
      __builtin_amdgcn_s_setprio(0);
    }
  }

  // epilogue: O^T[d][q]: d = dh*32 + (r&3) + 8*(r>>2) + 4*hi, q = lq
  float rl = 1.0f / l_run;
  #pragma unroll
  for (int dh = 0; dh < 2; ++dh)
    #pragma unroll
    for (int qd = 0; qd < 4; ++qd) {
      f16x4 ov;
      #pragma unroll
      for (int r = 0; r < 4; ++r) ov[r] = (f16)(o[dh][qd * 4 + r] * rl);
      int d0 = dh * 32 + qd * 8 + hi * 4;
      *reinterpret_cast<f16x4*>(
          &attn_out[(size_t)(b * S_ + qrow) * D_ + h * HD_ + d0]) = ov;
    }
}

// ---------------- launch --------------------------------------------
extern "C" void kernel_launch(void* const* d_in, const int* in_sizes, int n_in,
                              void* d_out, int out_size, void* d_ws, size_t ws_size,
                              hipStream_t stream) {
  const float* x    = (const float*)d_in[0];
  const int*   pos  = (const int*)d_in[1];
  const float* wqkv = (const float*)d_in[2];
  const float* wo   = (const float*)d_in[3];
  float* out = (float*)d_out;

  const size_t BHSD = (size_t)B_ * H_ * S_ * HD_;   // 8388608
  f16* xb    = (f16*)d_ws;                 // M_*D_
  f16* wqkvb = xb + (size_t)M_ * D_;       // NQKV_*D_
  f16* wob   = wqkvb + (size_t)NQKV_ * D_; // D_*D_
  f16* qb    = wob + (size_t)D_ * D_;      // BHSD
  f16* kb    = qb + BHSD;                  // BHSD
  f16* vtb   = kb + BHSD;                  // BHSD (B,H,hd,S)
  f16* attnb = vtb + BHSD;                 // BHSD
  float2* tab = (float2*)(attnb + BHSD);   // S_*32 float2 = 512 KB
  // total ~92 MB of d_ws

  cast3_kernel<<<6144, 256, 0, stream>>>(x, wqkv, wo, xb);
  trig_kernel<<<(S_ * 32) / 256, 256, 0, stream>>>(pos, tab);

  gemm_bt<0><<<(M_ / 128) * (NQKV_ / 128), 256, 0, stream>>>(
      xb, wqkvb, (void*)qb, tab, kb, vtb, M_, NQKV_, D_);

  attn_kernel<<<64 * 16, 256, 0, stream>>>(qb, kb, vtb, attnb);

  gemm_bt<1><<<(M_ / 128) * (D_ / 64), 256, 0, stream>>>(
      attnb, wob, (void*)out, nullptr, nullptr, nullptr, M_, D_, D_);
}

// Round 21
// 181.493 us; speedup vs baseline: 1.0392x; 1.0096x over previous
//
#include <hip/hip_runtime.h>

#define B_ 4
#define S_ 2048
#define D_ 1024
#define H_ 16
#define HD_ 64
#define M_ (B_*S_)      // 8192 rows
#define NQKV_ (3*D_)    // 3072

typedef _Float16 f16;
typedef __attribute__((ext_vector_type(4))) _Float16 f16x4;
typedef __attribute__((ext_vector_type(8))) _Float16 f16x8;
typedef __attribute__((ext_vector_type(4))) float f32x4;
typedef __attribute__((ext_vector_type(16))) float f32x16;
typedef __attribute__((ext_vector_type(2))) int i32x2;
typedef __attribute__((ext_vector_type(4))) int i32x4;

__device__ __forceinline__ void gload_lds16(const void* g, void* lds) {
  __builtin_amdgcn_global_load_lds(
      (const __attribute__((address_space(1))) void*)g,
      (__attribute__((address_space(3))) void*)lds, 16, 0, 0);
}

// ------- fused cast fp32 -> fp16 for x, W_qkv, W_o (outputs contiguous)
__global__ void cast3_kernel(const float* __restrict__ x,
                             const float* __restrict__ wqkv,
                             const float* __restrict__ wo,
                             f16* __restrict__ out) {
  size_t gi = (size_t)blockIdx.x * 2048 + (size_t)threadIdx.x * 8;
  const float* src;
  size_t off;
  if (gi < (size_t)M_ * D_)                       { src = x;    off = gi; }
  else if (gi < (size_t)M_ * D_ + (size_t)NQKV_ * D_) { src = wqkv; off = gi - (size_t)M_ * D_; }
  else                                            { src = wo;   off = gi - (size_t)M_ * D_ - (size_t)NQKV_ * D_; }
  float4 a = *reinterpret_cast<const float4*>(src + off);
  float4 b = *reinterpret_cast<const float4*>(src + off + 4);
  f16x8 o;
  o[0] = (f16)a.x; o[1] = (f16)a.y; o[2] = (f16)a.z; o[3] = (f16)a.w;
  o[4] = (f16)b.x; o[5] = (f16)b.y; o[6] = (f16)b.z; o[7] = (f16)b.w;
  *reinterpret_cast<f16x8*>(out + gi) = o;
}

// ---------------- RoPE trig table: tab[s][t] = {cos,sin}(pos[s]*invf(t))
__global__ void trig_kernel(const int* __restrict__ pos, float2* __restrict__ tab) {
  int idx = blockIdx.x * 256 + threadIdx.x;   // S_*32 threads
  int s = idx >> 5, t = idx & 31;
  float p = (float)pos[s];
  float invf = exp2f((float)t * -0.4152410118609203f);  // -log2(10000)/32
  float sn, cs;
  sincosf(p * invf, &sn, &cs);
  tab[idx] = float2{cs, sn};
}

// ---------------- GEMM C[m,n] = sum_k A[m,k]*Bt[n,k] ----------------
// (best-measured: swizzle-fixed counted-vmcnt ring-2, BK=32, 4 blocks/CU)
template <int MODE>
__global__ __launch_bounds__(256, 4)
void gemm_bt(const f16* __restrict__ A, const f16* __restrict__ Bt,
             void* __restrict__ Cout, const float2* __restrict__ tab,
             f16* __restrict__ kout, f16* __restrict__ vtout,
             int M, int N, int K) {
  constexpr int MI = (MODE == 0) ? 4 : 2;   // 16-row A-frags per wave
  constexpr int BP = (MODE == 0) ? 2 : 1;   // B staging passes; BN = 64*BP
  __shared__ __align__(16) f16 As[2][128 * 32];
  __shared__ __align__(16) f16 Bs[2][BP * 64 * 32];
  const int tid = threadIdx.x;
  const int w = tid >> 6, l = tid & 63;
  const int nM = M >> 7;
  const int bm = (int)(blockIdx.x % nM) << 7;
  const int bn = (int)(blockIdx.x / nM) * (BP * 64);
  const int wrow = (MODE == 0) ? ((w >> 1) << 6) : (w << 5);
  const int wcol = (MODE == 0) ? ((w & 1) << 6) : 0;
  const int lr = l & 15;
  const int lk = (l >> 4) << 3;     // 0,8,16,24
  const int orow = (l >> 4) << 2;
  const int swzr = ((lr >> 1) & 3) << 3;   // read-side XOR, key=(row>>1)&3
  const int NT = K >> 5;            // 32

  f32x4 acc[MI][4];
  #pragma unroll
  for (int i = 0; i < MI; ++i)
    #pragma unroll
    for (int j = 0; j < 4; ++j) acc[i][j] = f32x4{0.f, 0.f, 0.f, 0.f};

  const int srow4 = tid >> 2;            // 4 threads/row, 16B each
  const int ssw = ((tid & 3) * 8) ^ (((srow4 >> 1) & 3) << 3);

#define STAGE(t_) do {                                                    \
    const int buf_ = (t_) & 1; const int k0_ = (t_) << 5;                 \
    _Pragma("unroll")                                                     \
    for (int p = 0; p < 2; ++p)                                           \
      gload_lds16(A + (size_t)(bm + p * 64 + srow4) * K + k0_ + ssw,      \
                  (void*)(&As[buf_][(p * 256 + tid) * 8]));               \
    _Pragma("unroll")                                                     \
    for (int p = 0; p < BP; ++p)                                          \
      gload_lds16(Bt + (size_t)(bn + p * 64 + srow4) * K + k0_ + ssw,     \
                  (void*)(&Bs[buf_][(p * 256 + tid) * 8]));               \
  } while (0)

  STAGE(0);

  for (int t = 0; t < NT; ++t) {
    if (t + 1 < NT) {
      STAGE(t + 1);
      if constexpr (MODE == 0)
        asm volatile("s_waitcnt vmcnt(4)" ::: "memory");   // tile t landed
      else
        asm volatile("s_waitcnt vmcnt(3)" ::: "memory");
    } else {
      asm volatile("s_waitcnt vmcnt(0)" ::: "memory");
    }
    __builtin_amdgcn_sched_barrier(0);
    __builtin_amdgcn_s_barrier();       // tile t visible to all waves
    __builtin_amdgcn_sched_barrier(0);

    const f16* Asc = As[t & 1];
    const f16* Bsc = Bs[t & 1];
    f16x8 af[MI], bf[4];
    #pragma unroll
    for (int mi = 0; mi < MI; ++mi)
      af[mi] = *reinterpret_cast<const f16x8*>(
          Asc + (wrow + mi * 16 + lr) * 32 + (lk ^ swzr));
    #pragma unroll
    for (int ni = 0; ni < 4; ++ni)
      bf[ni] = *reinterpret_cast<const f16x8*>(
          Bsc + (wcol + ni * 16 + lr) * 32 + (lk ^ swzr));
    #pragma unroll
    for (int mi = 0; mi < MI; ++mi)
      #pragma unroll
      for (int ni = 0; ni < 4; ++ni)
        acc[mi][ni] = __builtin_amdgcn_mfma_f32_16x16x32_f16(bf[ni], af[mi], acc[mi][ni], 0, 0, 0);

    __builtin_amdgcn_sched_barrier(0);
    __builtin_amdgcn_s_barrier();       // all reads of buf[t&1] done
    __builtin_amdgcn_sched_barrier(0);
  }
#undef STAGE

  if (MODE == 0) {
    const int which = bn >> 10;                    // uniform per block
    const int h = ((bn + wcol) >> 6) & (H_ - 1);   // uniform per wave
    if (which < 2) {                               // Q or K: fused RoPE
      f16* dst = which ? kout : (f16*)Cout;
      const float qs = which ? 1.0f : 0.125f * 1.4426950408889634f;  // (1/8)*log2e
      #pragma unroll
      for (int mi = 0; mi < MI; ++mi) {
        int m = bm + wrow + mi * 16 + lr;
        int b = m >> 11, s = m & (S_ - 1);
        size_t rowbase = ((size_t)(b * H_ + h) * S_ + s) * HD_;
        const float4* trow = reinterpret_cast<const float4*>(tab + (size_t)s * 32);
        #pragma unroll
        for (int ni = 0; ni < 4; ++ni) {
          int d0 = ni * 16 + orow;                 // multiple of 4
          float4 cssn = trow[d0 >> 2];
          float x0 = acc[mi][ni][0], x1 = acc[mi][ni][1];
          float x2 = acc[mi][ni][2], x3 = acc[mi][ni][3];
          f16x4 ov;
          ov[0] = (f16)((x0 * cssn.x - x1 * cssn.y) * qs);
          ov[1] = (f16)((x1 * cssn.x + x0 * cssn.y) * qs);
          ov[2] = (f16)((x2 * cssn.z - x3 * cssn.w) * qs);
          ov[3] = (f16)((x3 * cssn.z + x2 * cssn.w) * qs);
          *reinterpret_cast<f16x4*>(&dst[rowbase + d0]) = ov;
        }
      }
    } else {                                       // V: direct transposed write
      #pragma unroll
      for (int mi = 0; mi < MI; ++mi) {
        int m = bm + wrow + mi * 16 + lr;
        int b = m >> 11, s = m & (S_ - 1);
        size_t base = (size_t)(b * H_ + h) * (HD_ * S_) + s;
        #pragma unroll
        for (int ni = 0; ni < 4; ++ni)
          #pragma unroll
          for (int r = 0; r < 4; ++r)
            vtout[base + (size_t)(ni * 16 + orow + r) * S_] = (f16)acc[mi][ni][r];
      }
    }
  } else {
    float* C = (float*)Cout;
    #pragma unroll
    for (int mi = 0; mi < MI; ++mi) {
      int m = bm + wrow + mi * 16 + lr;
      #pragma unroll
      for (int ni = 0; ni < 4; ++ni) {
        int n = bn + wcol + ni * 16 + orow;
        *reinterpret_cast<float4*>(&C[(size_t)m * N + n]) =
            float4{acc[mi][ni][0], acc[mi][ni][1], acc[mi][ni][2], acc[mi][ni][3]};
      }
    }
  }
}

// ---------------- flash attention (causal), 32x32 MFMA form ---------
// Best-measured version (80.1 us, reproduced 3x). Single-buffer K/V +
// __syncthreads loop, grid 1024 (4 blocks/CU), in-register P exchange,
// T13 defer-max. All alternatives measured worse or neutral: ring-2
// (82.4), pairing (94.3), split-KV+merge (+7 net), LDS-free (154.9),
// MFMA row-sum (98.5, spilled), setprio (82.2), explicit dbuf (neutral).
__global__ __launch_bounds__(256, 4)
void attn_kernel(const f16* __restrict__ q, const f16* __restrict__ k,
                 const f16* __restrict__ vt, f16* __restrict__ attn_out) {
  __shared__ __align__(16) f16 Ks[64 * 64];
  __shared__ __align__(16) f16 Vs[64 * 64];     // [d][kv]
  const int tid = threadIdx.x, wq = tid >> 6, l = tid & 63;
  const int lq = l & 31, hi = l >> 5;
  const int bh = blockIdx.x & 63;
  const int qt = 15 - (int)(blockIdx.x >> 6);   // heavy tiles first
  const int q0 = qt << 7;
  const size_t bhoff = (size_t)bh * (S_ * HD_);
  const size_t vtoff = (size_t)bh * (HD_ * S_);
  const int srow = tid >> 3;
  const int sc8 = (tid & 7) * 8;
  const int ssw = sc8 ^ ((srow & 7) << 3);      // swizzled source col
  const int swz = (lq & 7) << 3;                // read-side XOR
  const int h = bh & (H_ - 1), b = bh >> 4;
  const int wqmin = q0 + wq * 32;
  const int qrow = wqmin + lq;                  // this lane's q-row

  f16x8 qf[4];
  #pragma unroll
  for (int s = 0; s < 4; ++s)
    qf[s] = *reinterpret_cast<const f16x8*>(q + bhoff + (size_t)qrow * HD_ + s * 16 + hi * 8);

  f32x16 o[2];
  float m_run = -1e30f, l_run = 0.f;
  #pragma unroll
  for (int i = 0; i < 2; ++i)
    #pragma unroll
    for (int r = 0; r < 16; ++r) o[i][r] = 0.f;

  const int ntiles = 2 * qt + 2;
  for (int it = 0; it < ntiles; ++it) {
    const int kv0 = it << 6;
    __syncthreads();
    #pragma unroll
    for (int i = 0; i < 2; ++i) {
      gload_lds16(k + bhoff + (size_t)(kv0 + i * 32 + srow) * HD_ + ssw,
                  (void*)(Ks + (i * 256 + wq * 64) * 8));
      gload_lds16(vt + vtoff + (size_t)(i * 32 + srow) * S_ + kv0 + ssw,
                  (void*)(Vs + (i * 256 + wq * 64) * 8));
    }
    __syncthreads();

    if (kv0 <= wqmin + 31) {   // wave-uniform causal skip
      // S^T: D[col=q=lq][row = kh*32 + (r&3) + 8*(r>>2) + 4*hi]
      f32x16 sacc[2];
      #pragma unroll
      for (int kh = 0; kh < 2; ++kh) {
        #pragma unroll
        for (int r = 0; r < 16; ++r) sacc[kh][r] = 0.f;
        #pragma unroll
        for (int s = 0; s < 4; ++s) {
          f16x8 kf = *reinterpret_cast<const f16x8*>(
              Ks + (kh * 32 + lq) * 64 + ((s * 16 + hi * 8) ^ swz));
          sacc[kh] = __builtin_amdgcn_mfma_f32_32x32x16_f16(kf, qf[s], sacc[kh], 0, 0, 0);
        }
      }
      if (kv0 + 63 >= wqmin) {   // diagonal straddle: element mask
        #pragma unroll
        for (int kh = 0; kh < 2; ++kh)
          #pragma unroll
          for (int r = 0; r < 16; ++r) {
            int kvg = kv0 + kh * 32 + (r & 3) + 8 * (r >> 2) + 4 * hi;
            if (kvg > qrow) sacc[kh][r] = -1e30f;
          }
      }

      // online softmax with defer-max (T13, THR=8 in log2 units)
      float mloc = -1e30f;
      #pragma unroll
      for (int kh = 0; kh < 2; ++kh)
        #pragma unroll
        for (int r = 0; r < 16; ++r) mloc = fmaxf(mloc, sacc[kh][r]);
      mloc = fmaxf(mloc, __shfl_xor(mloc, 32));
      if (__any(mloc > m_run + 8.f)) {
        float mn = fmaxf(m_run, mloc);
        float scale = exp2f(m_run - mn);
        m_run = mn;
        l_run *= scale;
        #pragma unroll
        for (int i = 0; i < 2; ++i)
          #pragma unroll
          for (int r = 0; r < 16; ++r) o[i][r] *= scale;
      }
      float sloc = 0.f;
      #pragma unroll
      for (int kh = 0; kh < 2; ++kh)
        #pragma unroll
        for (int r = 0; r < 16; ++r) {
          sacc[kh][r] = exp2f(sacc[kh][r] - m_run);
          sloc += sacc[kh][r];
        }
      sloc += __shfl_xor(sloc, 32);
      l_run += sloc;

      // P -> PV B-fragments fully in-register:
      // pf[ks][j] = P[lq][16*ks + 8*hi + j]
      f16x8 pf[4];
      #pragma unroll
      for (int ks = 0; ks < 4; ++ks) {
        const int khh = ks >> 1;
        f16x4 pA, pB;
        #pragma unroll
        for (int r = 0; r < 4; ++r) {
          pA[r] = (f16)sacc[khh][(ks & 1) * 8 + r];
          pB[r] = (f16)sacc[khh][(ks & 1) * 8 + 4 + r];
        }
        i32x2 ia = __builtin_bit_cast(i32x2, pA);
        i32x2 ib = __builtin_bit_cast(i32x2, pB);
        i32x2 oth, rcv, lo2, hh2;
        oth.x = hi ? ia.x : ib.x;
        oth.y = hi ? ia.y : ib.y;
        rcv.x = __shfl_xor(oth.x, 32);
        rcv.y = __shfl_xor(oth.y, 32);
        lo2.x = hi ? rcv.x : ia.x;
        lo2.y = hi ? rcv.y : ia.y;
        hh2.x = hi ? ib.x : rcv.x;
        hh2.y = hi ? ib.y : rcv.y;
        i32x4 full{lo2.x, lo2.y, hh2.x, hh2.y};
        pf[ks] = __builtin_bit_cast(f16x8, full);
      }

      // O^T += V^T @ P^T
      #pragma unroll
      for (int dh = 0; dh < 2; ++dh)
        #pragma unroll
        for (int s2 = 0; s2 < 4; ++s2) {
          f16x8 vf = *reinterpret_cast<const f16x8*>(
              Vs + (dh * 32 + lq) * 64 + ((s2 * 16 + hi * 8) ^ swz));
          o[dh] = __builtin_amdgcn_mfma_f32_32x32x16_f16(vf, pf[s2], o[dh], 0, 0, 0);
        }
    }
  }

  // epilogue: O^T[d][q]: d = dh*32 + (r&3) + 8*(r>>2) + 4*hi, q = lq
  float rl = 1.0f / l_run;
  #pragma unroll
  for (int dh = 0; dh < 2; ++dh)
    #pragma unroll
    for (int qd = 0; qd < 4; ++qd) {
      f16x4 ov;
      #pragma unroll
      for (int r = 0; r < 4; ++r) ov[r] = (f16)(o[dh][qd * 4 + r] * rl);
      int d0 = dh * 32 + qd * 8 + hi * 4;
      *reinterpret_cast<f16x4*>(
          &attn_out[(size_t)(b * S_ + qrow) * D_ + h * HD_ + d0]) = ov;
    }
}

// ---------------- launch --------------------------------------------
extern "C" void kernel_launch(void* const* d_in, const int* in_sizes, int n_in,
                              void* d_out, int out_size, void* d_ws, size_t ws_size,
                              hipStream_t stream) {
  const float* x    = (const float*)d_in[0];
  const int*   pos  = (const int*)d_in[1];
  const float* wqkv = (const float*)d_in[2];
  const float* wo   = (const float*)d_in[3];
  float* out = (float*)d_out;

  const size_t BHSD = (size_t)B_ * H_ * S_ * HD_;   // 8388608
  f16* xb    = (f16*)d_ws;                 // M_*D_
  f16* wqkvb = xb + (size_t)M_ * D_;       // NQKV_*D_
  f16* wob   = wqkvb + (size_t)NQKV_ * D_; // D_*D_
  f16* qb    = wob + (size_t)D_ * D_;      // BHSD
  f16* kb    = qb + BHSD;                  // BHSD
  f16* vtb   = kb + BHSD;                  // BHSD (B,H,hd,S)
  f16* attnb = vtb + BHSD;                 // BHSD
  float2* tab = (float2*)(attnb + BHSD);   // S_*32 float2 = 512 KB
  // total ~92 MB of d_ws

  cast3_kernel<<<6144, 256, 0, stream>>>(x, wqkv, wo, xb);
  trig_kernel<<<(S_ * 32) / 256, 256, 0, stream>>>(pos, tab);

  gemm_bt<0><<<(M_ / 128) * (NQKV_ / 128), 256, 0, stream>>>(
      xb, wqkvb, (void*)qb, tab, kb, vtb, M_, NQKV_, D_);

  attn_kernel<<<64 * 16, 256, 0, stream>>>(qb, kb, vtb, attnb);

  gemm_bt<1><<<(M_ / 128) * (D_ / 64), 256, 0, stream>>>(
      attnb, wob, (void*)out, nullptr, nullptr, nullptr, M_, D_, D_);
}